// Round 1
// 6590.061 us; speedup vs baseline: 1.3880x; 1.3880x over previous
//
#include <hip/hip_runtime.h>
#include <math.h>

#define BB 32          // batch
#define TT 128         // time steps
#define EE 512         // embed dim
#define HH 1024        // hidden
#define VV 32000       // vocab
#define GG (4*HH)      // 4096 gates
#define MBT (BB*TT)    // 4096 rows
#define NS 16          // K-split slices for recurrent GEMM

typedef short bf16x8 __attribute__((ext_vector_type(8)));
typedef float f32x4  __attribute__((ext_vector_type(4)));

// ---------------------------------------------------------------------------
// Generic NT SGEMM (fp32 VALU): kept for xg GEMM and as FC fallback.
// ---------------------------------------------------------------------------
template<bool GATHER>
__global__ __launch_bounds__(256)
void sgemm_nt(const float* __restrict__ A, const float* __restrict__ Bw,
              float* __restrict__ C,
              const int* __restrict__ rows,
              const float* __restrict__ bias0, const float* __restrict__ bias1,
              int M, int N, int K)
{
    __shared__ float As[16][132];
    __shared__ float Bs[16][132];

    const int tid = threadIdx.x;
    const int tx = tid & 15;
    const int ty = tid >> 4;
    const int bm = blockIdx.y * 128;
    const int bn = blockIdx.x * 128;

    const int sr = tid & 127;
    const int sq = (tid >> 7) * 8;

    const float* aBase;
    if (GATHER) aBase = A + (size_t)rows[bm + sr] * K;
    else        aBase = A + (size_t)(bm + sr) * K;
    const float* bBase = Bw + (size_t)(bn + sr) * K;

    float acc[8][8];
#pragma unroll
    for (int i = 0; i < 8; ++i)
#pragma unroll
        for (int j = 0; j < 8; ++j) acc[i][j] = 0.f;

    for (int k0 = 0; k0 < K; k0 += 16) {
        float4 av0 = *(const float4*)(aBase + k0 + sq);
        float4 av1 = *(const float4*)(aBase + k0 + sq + 4);
        float4 bv0 = *(const float4*)(bBase + k0 + sq);
        float4 bv1 = *(const float4*)(bBase + k0 + sq + 4);

        __syncthreads();
        As[sq+0][sr] = av0.x; As[sq+1][sr] = av0.y;
        As[sq+2][sr] = av0.z; As[sq+3][sr] = av0.w;
        As[sq+4][sr] = av1.x; As[sq+5][sr] = av1.y;
        As[sq+6][sr] = av1.z; As[sq+7][sr] = av1.w;
        Bs[sq+0][sr] = bv0.x; Bs[sq+1][sr] = bv0.y;
        Bs[sq+2][sr] = bv0.z; Bs[sq+3][sr] = bv0.w;
        Bs[sq+4][sr] = bv1.x; Bs[sq+5][sr] = bv1.y;
        Bs[sq+6][sr] = bv1.z; Bs[sq+7][sr] = bv1.w;
        __syncthreads();

#pragma unroll
        for (int k = 0; k < 16; ++k) {
            float a[8], b[8];
            *(float4*)&a[0] = *(const float4*)&As[k][ty*8];
            *(float4*)&a[4] = *(const float4*)&As[k][ty*8 + 4];
            *(float4*)&b[0] = *(const float4*)&Bs[k][tx*8];
            *(float4*)&b[4] = *(const float4*)&Bs[k][tx*8 + 4];
#pragma unroll
            for (int i = 0; i < 8; ++i)
#pragma unroll
                for (int j = 0; j < 8; ++j)
                    acc[i][j] = fmaf(a[i], b[j], acc[i][j]);
        }
    }

    float bz[8];
#pragma unroll
    for (int j = 0; j < 8; ++j) {
        float bb = 0.f;
        if (bias0) bb += bias0[bn + tx*8 + j];
        if (bias1) bb += bias1[bn + tx*8 + j];
        bz[j] = bb;
    }
#pragma unroll
    for (int i = 0; i < 8; ++i) {
        float* cp = C + (size_t)(bm + ty*8 + i) * N + bn + tx*8;
        float4 o0, o1;
        o0.x = acc[i][0] + bz[0]; o0.y = acc[i][1] + bz[1];
        o0.z = acc[i][2] + bz[2]; o0.w = acc[i][3] + bz[3];
        o1.x = acc[i][4] + bz[4]; o1.y = acc[i][5] + bz[5];
        o1.z = acc[i][6] + bz[6]; o1.w = acc[i][7] + bz[7];
        *(float4*)cp = o0;
        *(float4*)(cp + 4) = o1;
    }
}

// ---------------------------------------------------------------------------
// Transpose W_hh [G][H] -> Wt [H][G]
// ---------------------------------------------------------------------------
__global__ __launch_bounds__(256)
void transpose_whh(const float* __restrict__ W, float* __restrict__ Wt)
{
    __shared__ float tile[32][33];
    const int bx = blockIdx.x * 32;
    const int by = blockIdx.y * 32;
    const int x = threadIdx.x;
    const int y = threadIdx.y;
#pragma unroll
    for (int i = 0; i < 32; i += 8)
        tile[y + i][x] = W[(size_t)(by + y + i) * HH + bx + x];
    __syncthreads();
#pragma unroll
    for (int i = 0; i < 32; i += 8)
        Wt[(size_t)(bx + y + i) * GG + by + x] = tile[x][y + i];
}

// ---------------------------------------------------------------------------
// Recurrent partial GEMM
// ---------------------------------------------------------------------------
__global__ __launch_bounds__(256)
void lstm_partial(const float* __restrict__ Wt, const float* __restrict__ h,
                  float* __restrict__ part)
{
    const int g  = blockIdx.x * 256 + threadIdx.x;
    const int k0 = blockIdx.y * (HH / NS);

    float acc[BB];
#pragma unroll
    for (int b = 0; b < BB; ++b) acc[b] = 0.f;

    for (int kk = 0; kk < HH / NS; kk += 4) {
        const float w0 = Wt[(size_t)(k0 + kk + 0) * GG + g];
        const float w1 = Wt[(size_t)(k0 + kk + 1) * GG + g];
        const float w2 = Wt[(size_t)(k0 + kk + 2) * GG + g];
        const float w3 = Wt[(size_t)(k0 + kk + 3) * GG + g];
#pragma unroll
        for (int b = 0; b < BB; ++b) {
            float4 hv = *(const float4*)&h[b * HH + k0 + kk];
            float a = acc[b];
            a = fmaf(hv.x, w0, a);
            a = fmaf(hv.y, w1, a);
            a = fmaf(hv.z, w2, a);
            a = fmaf(hv.w, w3, a);
            acc[b] = a;
        }
    }
#pragma unroll
    for (int b = 0; b < BB; ++b)
        part[((size_t)blockIdx.y * BB + b) * GG + g] = acc[b];
}

// ---------------------------------------------------------------------------
// Gate nonlinearities + state update
// ---------------------------------------------------------------------------
__global__ __launch_bounds__(256)
void lstm_cell(const float* __restrict__ xg, const float* __restrict__ part,
               float* __restrict__ hbuf, float* __restrict__ cbuf,
               float* __restrict__ hs, int t)
{
    const int id = blockIdx.x * 256 + threadIdx.x;
    const int b  = id >> 10;
    const int hh = id & (HH - 1);
    const int m  = b * TT + t;

    float gv[4];
#pragma unroll
    for (int gate = 0; gate < 4; ++gate) {
        const int base = gate * HH + hh;
        float v = xg[(size_t)m * GG + base];
#pragma unroll
        for (int s = 0; s < NS; ++s)
            v += part[((size_t)s * BB + b) * GG + base];
        gv[gate] = v;
    }

    const float ig = 1.f / (1.f + expf(-gv[0]));
    const float fg = 1.f / (1.f + expf(-gv[1]));
    const float gg = tanhf(gv[2]);
    const float og = 1.f / (1.f + expf(-gv[3]));

    const float c = fg * cbuf[id] + ig * gg;
    const float hn = og * tanhf(c);
    cbuf[id] = c;
    hbuf[id] = hn;
    hs[(size_t)m * HH + hh] = hn;
}

// ---------------------------------------------------------------------------
// Split fp32 -> (bf16 hi, bf16 lo), RNE both.  x ~= hi + lo to ~17 bits.
// Grid sized exactly: n = grid.x * 1024 elements.
// ---------------------------------------------------------------------------
__global__ __launch_bounds__(256)
void split_f32_bf16(const float* __restrict__ src,
                    unsigned short* __restrict__ hi,
                    unsigned short* __restrict__ lo)
{
    const size_t i = ((size_t)blockIdx.x * 256 + threadIdx.x) * 4;
    float4 v = *(const float4*)(src + i);
    float f[4] = {v.x, v.y, v.z, v.w};
    unsigned short h[4], l[4];
#pragma unroll
    for (int q = 0; q < 4; ++q) {
        unsigned u = __float_as_uint(f[q]);
        unsigned r = u + 0x7fff + ((u >> 16) & 1);          // RNE to bf16
        h[q] = (unsigned short)(r >> 16);
        float hf = __uint_as_float((unsigned)h[q] << 16);
        float res = f[q] - hf;
        unsigned u2 = __float_as_uint(res);
        unsigned r2 = u2 + 0x7fff + ((u2 >> 16) & 1);
        l[q] = (unsigned short)(r2 >> 16);
    }
    *(ushort4*)(hi + i) = make_ushort4(h[0], h[1], h[2], h[3]);
    *(ushort4*)(lo + i) = make_ushort4(l[0], l[1], l[2], l[3]);
}

// ---------------------------------------------------------------------------
// FC projection via bf16-split MFMA:
//   C[m][n] = sum_k A[m][k]*B[n][k] + bias[n]
//   A = hs (4096x1024), B = fc_w (32000x1024), fp32 accuracy via
//   ahi*bhi + alo*bhi + ahi*blo  (3x mfma_f32_16x16x32_bf16).
// 128x128 tile, BK=32, 4 waves in 2x2, each wave 64x64 (4x4 frags).
// Staging: global_load_lds width=16, linear LDS [row][k], 64B row stride.
// blockIdx.x = m-tile (fast) so consecutive blocks share the B panel.
// ---------------------------------------------------------------------------
__device__ __forceinline__ void gload16(const void* g, void* l)
{
    __builtin_amdgcn_global_load_lds(
        (const __attribute__((address_space(1))) void*)g,
        (__attribute__((address_space(3))) void*)l,
        16, 0, 0);
}

__global__ __launch_bounds__(256, 2)
void mfma_fc(const unsigned short* __restrict__ Ahg,
             const unsigned short* __restrict__ Alg,
             const unsigned short* __restrict__ Bhg,
             const unsigned short* __restrict__ Blg,
             const float* __restrict__ bias,
             float* __restrict__ C)
{
    __shared__ unsigned short AsH[128*32], AsL[128*32];
    __shared__ unsigned short BsH[128*32], BsL[128*32];

    const int tid  = threadIdx.x;
    const int w    = tid >> 6;
    const int lane = tid & 63;
    const int wm   = w >> 1;        // 2x2 wave grid
    const int wn   = w & 1;
    const int bm   = blockIdx.x * 128;
    const int bn   = blockIdx.y * 128;

    // staging: each lane loads 16B; 4 lanes per 32-elem (64B) row.
    // wave w fills rows [w*32, w*32+32) of each buffer via 2 instrs.
    const int srow = lane >> 2;            // 0..15
    const int skq  = (lane & 3) * 8;       // k elem offset 0/8/16/24
    const size_t aoff = (size_t)(bm + w*32 + srow) * HH + skq;
    const size_t boff = (size_t)(bn + w*32 + srow) * HH + skq;
    const int lb = w * 32 * 32;            // wave's LDS chunk (elements)

    // fragment read: lane holds 8 contiguous k at row (lane&15)
    const int fr = lane & 15;
    const int fk = (lane >> 4) * 8;
    const int ab = (wm*64 + fr)*32 + fk;
    const int bb = (wn*64 + fr)*32 + fk;

    f32x4 acc[4][4];
#pragma unroll
    for (int i = 0; i < 4; ++i)
#pragma unroll
        for (int j = 0; j < 4; ++j)
            acc[i][j] = (f32x4){0.f, 0.f, 0.f, 0.f};

    for (int k0 = 0; k0 < HH; k0 += 32) {
        __syncthreads();                       // prev compute done
        gload16(Ahg + aoff + k0,           AsH + lb);
        gload16(Ahg + aoff + 16*HH + k0,   AsH + lb + 512);
        gload16(Alg + aoff + k0,           AsL + lb);
        gload16(Alg + aoff + 16*HH + k0,   AsL + lb + 512);
        gload16(Bhg + boff + k0,           BsH + lb);
        gload16(Bhg + boff + 16*HH + k0,   BsH + lb + 512);
        gload16(Blg + boff + k0,           BsL + lb);
        gload16(Blg + boff + 16*HH + k0,   BsL + lb + 512);
        __syncthreads();                       // vmcnt(0) drained by compiler

        bf16x8 ah[4], al[4], bh[4], bl[4];
#pragma unroll
        for (int i = 0; i < 4; ++i) {
            ah[i] = *(const bf16x8*)(AsH + ab + i*512);
            al[i] = *(const bf16x8*)(AsL + ab + i*512);
            bh[i] = *(const bf16x8*)(BsH + bb + i*512);
            bl[i] = *(const bf16x8*)(BsL + bb + i*512);
        }
#pragma unroll
        for (int i = 0; i < 4; ++i)
#pragma unroll
            for (int j = 0; j < 4; ++j) {
                acc[i][j] = __builtin_amdgcn_mfma_f32_16x16x32_bf16(ah[i], bh[j], acc[i][j], 0, 0, 0);
                acc[i][j] = __builtin_amdgcn_mfma_f32_16x16x32_bf16(al[i], bh[j], acc[i][j], 0, 0, 0);
                acc[i][j] = __builtin_amdgcn_mfma_f32_16x16x32_bf16(ah[i], bl[j], acc[i][j], 0, 0, 0);
            }
    }

    // C/D layout (verified): col = lane&15, row = (lane>>4)*4 + reg
    const int rr = (lane >> 4) * 4;
#pragma unroll
    for (int j = 0; j < 4; ++j) {
        const int col = bn + wn*64 + j*16 + fr;
        const float bz = bias[col];
#pragma unroll
        for (int i = 0; i < 4; ++i) {
            const int row = bm + wm*64 + i*16 + rr;
            float* cp = C + (size_t)row * VV + col;
#pragma unroll
            for (int r = 0; r < 4; ++r)
                cp[(size_t)r * VV] = acc[i][j][r] + bz;
        }
    }
}

// ---------------------------------------------------------------------------
extern "C" void kernel_launch(void* const* d_in, const int* in_sizes, int n_in,
                              void* d_out, int out_size, void* d_ws, size_t ws_size,
                              hipStream_t stream)
{
    const int*   x     = (const int*)d_in[0];
    const float* embed = (const float*)d_in[1];
    const float* W_ih  = (const float*)d_in[2];
    const float* W_hh  = (const float*)d_in[3];
    const float* b_ih  = (const float*)d_in[4];
    const float* b_hh  = (const float*)d_in[5];
    const float* fc_w  = (const float*)d_in[6];
    const float* fc_b  = (const float*)d_in[7];
    float* out = (float*)d_out;

    char* ws = (char*)d_ws;
    float* xg   = (float*)ws;  ws += (size_t)MBT * GG * 4;     // 64 MB
    float* Wt   = (float*)ws;  ws += (size_t)HH * GG * 4;      // 16.8 MB
    float* hs   = (float*)ws;  ws += (size_t)MBT * HH * 4;     // 16.8 MB
    float* part = (float*)ws;  ws += (size_t)NS * BB * GG * 4; // 8.4 MB
    float* hbuf = (float*)ws;  ws += (size_t)BB * HH * 4;
    float* cbuf = (float*)ws;  ws += (size_t)BB * HH * 4;
    unsigned short* Ah = (unsigned short*)ws; ws += (size_t)MBT * HH * 2;  // 8.4 MB
    unsigned short* Al = (unsigned short*)ws; ws += (size_t)MBT * HH * 2;  // 8.4 MB
    unsigned short* Bh = (unsigned short*)ws; ws += (size_t)VV * HH * 2;   // 65.5 MB
    unsigned short* Bl = (unsigned short*)ws; ws += (size_t)VV * HH * 2;   // 65.5 MB
    const size_t need = (size_t)(ws - (char*)d_ws);
    const bool use_mfma = (ws_size >= need);

    hipMemsetAsync(hbuf, 0, (size_t)BB * HH * 4 * 2, stream);

    transpose_whh<<<dim3(HH / 32, GG / 32), dim3(32, 8), 0, stream>>>(W_hh, Wt);

    if (use_mfma) {
        // fc_w -> bf16 hi/lo (32000*1024 / 1024 = 32000 blocks)
        split_f32_bf16<<<dim3((VV * HH) / 1024), 256, 0, stream>>>(fc_w, Bh, Bl);
    }

    // xg = embed[x] @ W_ih^T + b_ih + b_hh
    sgemm_nt<true><<<dim3(GG / 128, MBT / 128), 256, 0, stream>>>(
        embed, W_ih, xg, x, b_ih, b_hh, MBT, GG, EE);

    // sequential LSTM scan
    for (int t = 0; t < TT; ++t) {
        lstm_partial<<<dim3(GG / 256, NS), 256, 0, stream>>>(Wt, hbuf, part);
        lstm_cell<<<dim3(BB * HH / 256), 256, 0, stream>>>(xg, part, hbuf, cbuf, hs, t);
    }

    if (use_mfma) {
        // hs -> bf16 hi/lo, then FC via bf16-split MFMA
        split_f32_bf16<<<dim3((MBT * HH) / 1024), 256, 0, stream>>>(hs, Ah, Al);
        mfma_fc<<<dim3(MBT / 128, VV / 128), 256, 0, stream>>>(Ah, Al, Bh, Bl, fc_b, out);
    } else {
        sgemm_nt<false><<<dim3(VV / 128, MBT / 128), 256, 0, stream>>>(
            hs, fc_w, out, nullptr, fc_b, nullptr, MBT, VV, HH);
    }
}

// Round 3
// 3996.360 us; speedup vs baseline: 2.2888x; 1.6490x over previous
//
#include <hip/hip_runtime.h>
#include <math.h>

#define BB 32          // batch
#define TT 128         // time steps
#define EE 512         // embed dim
#define HH 1024        // hidden
#define VV 32000       // vocab
#define GG (4*HH)      // 4096 gates
#define MBT (BB*TT)    // 4096 rows
#define JB 8           // hidden-cols per lstm_step block

typedef short bf16x8 __attribute__((ext_vector_type(8)));
typedef float f32x4  __attribute__((ext_vector_type(4)));

// ---------------------------------------------------------------------------
// Generic NT SGEMM (fp32 VALU): kept for xg GEMM and as FC fallback.
// ---------------------------------------------------------------------------
template<bool GATHER>
__global__ __launch_bounds__(256)
void sgemm_nt(const float* __restrict__ A, const float* __restrict__ Bw,
              float* __restrict__ C,
              const int* __restrict__ rows,
              const float* __restrict__ bias0, const float* __restrict__ bias1,
              int M, int N, int K)
{
    __shared__ float As[16][132];
    __shared__ float Bs[16][132];

    const int tid = threadIdx.x;
    const int tx = tid & 15;
    const int ty = tid >> 4;
    const int bm = blockIdx.y * 128;
    const int bn = blockIdx.x * 128;

    const int sr = tid & 127;
    const int sq = (tid >> 7) * 8;

    const float* aBase;
    if (GATHER) aBase = A + (size_t)rows[bm + sr] * K;
    else        aBase = A + (size_t)(bm + sr) * K;
    const float* bBase = Bw + (size_t)(bn + sr) * K;

    float acc[8][8];
#pragma unroll
    for (int i = 0; i < 8; ++i)
#pragma unroll
        for (int j = 0; j < 8; ++j) acc[i][j] = 0.f;

    for (int k0 = 0; k0 < K; k0 += 16) {
        float4 av0 = *(const float4*)(aBase + k0 + sq);
        float4 av1 = *(const float4*)(aBase + k0 + sq + 4);
        float4 bv0 = *(const float4*)(bBase + k0 + sq);
        float4 bv1 = *(const float4*)(bBase + k0 + sq + 4);

        __syncthreads();
        As[sq+0][sr] = av0.x; As[sq+1][sr] = av0.y;
        As[sq+2][sr] = av0.z; As[sq+3][sr] = av0.w;
        As[sq+4][sr] = av1.x; As[sq+5][sr] = av1.y;
        As[sq+6][sr] = av1.z; As[sq+7][sr] = av1.w;
        Bs[sq+0][sr] = bv0.x; Bs[sq+1][sr] = bv0.y;
        Bs[sq+2][sr] = bv0.z; Bs[sq+3][sr] = bv0.w;
        Bs[sq+4][sr] = bv1.x; Bs[sq+5][sr] = bv1.y;
        Bs[sq+6][sr] = bv1.z; Bs[sq+7][sr] = bv1.w;
        __syncthreads();

#pragma unroll
        for (int k = 0; k < 16; ++k) {
            float a[8], b[8];
            *(float4*)&a[0] = *(const float4*)&As[k][ty*8];
            *(float4*)&a[4] = *(const float4*)&As[k][ty*8 + 4];
            *(float4*)&b[0] = *(const float4*)&Bs[k][tx*8];
            *(float4*)&b[4] = *(const float4*)&Bs[k][tx*8 + 4];
#pragma unroll
            for (int i = 0; i < 8; ++i)
#pragma unroll
                for (int j = 0; j < 8; ++j)
                    acc[i][j] = fmaf(a[i], b[j], acc[i][j]);
        }
    }

    float bz[8];
#pragma unroll
    for (int j = 0; j < 8; ++j) {
        float bb = 0.f;
        if (bias0) bb += bias0[bn + tx*8 + j];
        if (bias1) bb += bias1[bn + tx*8 + j];
        bz[j] = bb;
    }
#pragma unroll
    for (int i = 0; i < 8; ++i) {
        float* cp = C + (size_t)(bm + ty*8 + i) * N + bn + tx*8;
        float4 o0, o1;
        o0.x = acc[i][0] + bz[0]; o0.y = acc[i][1] + bz[1];
        o0.z = acc[i][2] + bz[2]; o0.w = acc[i][3] + bz[3];
        o1.x = acc[i][4] + bz[4]; o1.y = acc[i][5] + bz[5];
        o1.z = acc[i][6] + bz[6]; o1.w = acc[i][7] + bz[7];
        *(float4*)cp = o0;
        *(float4*)(cp + 4) = o1;
    }
}

// ---------------------------------------------------------------------------
// Split fp32 -> (bf16 hi, bf16 lo), RNE both.  x ~= hi + lo to ~17 bits.
// n = grid.x * 1024 elements (exact).
// ---------------------------------------------------------------------------
__global__ __launch_bounds__(256)
void split_f32_bf16(const float* __restrict__ src,
                    unsigned short* __restrict__ hi,
                    unsigned short* __restrict__ lo)
{
    const size_t i = ((size_t)blockIdx.x * 256 + threadIdx.x) * 4;
    float4 v = *(const float4*)(src + i);
    float f[4] = {v.x, v.y, v.z, v.w};
    unsigned short h[4], l[4];
#pragma unroll
    for (int q = 0; q < 4; ++q) {
        unsigned u = __float_as_uint(f[q]);
        unsigned r = u + 0x7fff + ((u >> 16) & 1);          // RNE to bf16
        h[q] = (unsigned short)(r >> 16);
        float hf = __uint_as_float((unsigned)h[q] << 16);
        float res = f[q] - hf;
        unsigned u2 = __float_as_uint(res);
        unsigned r2 = u2 + 0x7fff + ((u2 >> 16) & 1);
        l[q] = (unsigned short)(r2 >> 16);
    }
    *(ushort4*)(hi + i) = make_ushort4(h[0], h[1], h[2], h[3]);
    *(ushort4*)(lo + i) = make_ushort4(l[0], l[1], l[2], l[3]);
}

// ---------------------------------------------------------------------------
// Fused LSTM step: gates GEMM (bf16-split MFMA) + nonlinearity + state update.
// One launch per timestep; the launch boundary is the only h(t-1)->h(t) sync.
//
// Block owns JB=8 hidden cols j0..j0+7 and their FOUR gate rows
// {j, H+j, 2H+j, 3H+j} -> 32 N-cols total, M=32 batch, K=1024.
// 4 waves in 2x2: wave (mw,nw) computes m-frag mw (16 b) x n-frag nw (16 cols).
// B-frag col c (lane&15) maps to W_hh row  gate*H + j0 + (c&7),
// gate = 2*nw + (c>>3)  => global col index cg = nw*16+c = gate*8 + (c&7).
// W_hh is consumed as bf16 hi/lo [G][H] row-major (no transpose needed).
// h is carried as bf16 hi/lo ping-pong buffers; cell writes hs_hi/hs_lo for
// the FC MFMA directly (no separate split pass) + hs32 for the FC fallback.
// ---------------------------------------------------------------------------
__global__ __launch_bounds__(256)
void lstm_step(const unsigned short* __restrict__ Wh,
               const unsigned short* __restrict__ Wl,
               const unsigned short* __restrict__ hHi,
               const unsigned short* __restrict__ hLi,
               const float* __restrict__ xg,
               float* __restrict__ cbuf,
               unsigned short* __restrict__ hHo,
               unsigned short* __restrict__ hLo,
               unsigned short* __restrict__ hsH,
               unsigned short* __restrict__ hsL,
               float* __restrict__ hs32,
               int t)
{
    __shared__ float gl[32][36];   // [b][gate*8+jj], pad 36 vs bank conflicts

    const int tid  = threadIdx.x;
    const int lane = tid & 63;
    const int w    = tid >> 6;
    const int mw   = w >> 1;
    const int nw   = w & 1;
    const int j0   = blockIdx.x * JB;
    const int c    = lane & 15;
    const int kq   = (lane >> 4) * 8;          // k elem offset 0/8/16/24

    const int gate = 2 * nw + (c >> 3);
    const size_t grow = (size_t)(gate * HH + j0 + (c & 7));

    const bf16x8* ap_h = (const bf16x8*)(hHi + (size_t)(mw * 16 + c) * HH + kq);
    const bf16x8* ap_l = (const bf16x8*)(hLi + (size_t)(mw * 16 + c) * HH + kq);
    const bf16x8* bp_h = (const bf16x8*)(Wh + grow * HH + kq);
    const bf16x8* bp_l = (const bf16x8*)(Wl + grow * HH + kq);

    f32x4 acc = (f32x4){0.f, 0.f, 0.f, 0.f};
#pragma unroll 8
    for (int k = 0; k < HH / 8; k += 4) {      // 32 k-steps of 32 elems
        bf16x8 ah = ap_h[k];
        bf16x8 al = ap_l[k];
        bf16x8 bh = bp_h[k];
        bf16x8 bl = bp_l[k];
        acc = __builtin_amdgcn_mfma_f32_16x16x32_bf16(ah, bh, acc, 0, 0, 0);
        acc = __builtin_amdgcn_mfma_f32_16x16x32_bf16(al, bh, acc, 0, 0, 0);
        acc = __builtin_amdgcn_mfma_f32_16x16x32_bf16(ah, bl, acc, 0, 0, 0);
    }

    // C/D layout: col = lane&15 (= c), row = (lane>>4)*4 + reg
    const int cg   = nw * 16 + c;              // == gate*8 + (c&7)
    const int brow = mw * 16 + (lane >> 4) * 4;
    gl[brow + 0][cg] = acc[0];
    gl[brow + 1][cg] = acc[1];
    gl[brow + 2][cg] = acc[2];
    gl[brow + 3][cg] = acc[3];
    __syncthreads();

    // cell update: one thread per (b, jj)
    const int b  = tid >> 3;                   // 0..31
    const int jj = tid & 7;
    const int m  = b * TT + t;

    const float gi = gl[b][0 * 8 + jj] + xg[(size_t)m * GG + 0 * HH + j0 + jj];
    const float gf = gl[b][1 * 8 + jj] + xg[(size_t)m * GG + 1 * HH + j0 + jj];
    const float gc = gl[b][2 * 8 + jj] + xg[(size_t)m * GG + 2 * HH + j0 + jj];
    const float go = gl[b][3 * 8 + jj] + xg[(size_t)m * GG + 3 * HH + j0 + jj];

    const float ig = 1.f / (1.f + expf(-gi));
    const float fg = 1.f / (1.f + expf(-gf));
    const float gg = tanhf(gc);
    const float og = 1.f / (1.f + expf(-go));

    const int idx = b * HH + j0 + jj;
    const float cn = fg * cbuf[idx] + ig * gg;
    const float hn = og * tanhf(cn);
    cbuf[idx] = cn;

    // split h to bf16 hi/lo (RNE both)
    unsigned u = __float_as_uint(hn);
    unsigned r = u + 0x7fff + ((u >> 16) & 1);
    unsigned short hhi = (unsigned short)(r >> 16);
    float hf = __uint_as_float((unsigned)hhi << 16);
    float res = hn - hf;
    unsigned u2 = __float_as_uint(res);
    unsigned r2 = u2 + 0x7fff + ((u2 >> 16) & 1);
    unsigned short hlo = (unsigned short)(r2 >> 16);

    hHo[idx] = hhi;
    hLo[idx] = hlo;
    const size_t hsoff = (size_t)m * HH + j0 + jj;
    hsH[hsoff]  = hhi;
    hsL[hsoff]  = hlo;
    hs32[hsoff] = hn;
}

// ---------------------------------------------------------------------------
// FC projection via bf16-split MFMA (unchanged from prev round).
// ---------------------------------------------------------------------------
__device__ __forceinline__ void gload16(const void* g, void* l)
{
    __builtin_amdgcn_global_load_lds(
        (const __attribute__((address_space(1))) void*)g,
        (__attribute__((address_space(3))) void*)l,
        16, 0, 0);
}

__global__ __launch_bounds__(256, 2)
void mfma_fc(const unsigned short* __restrict__ Ahg,
             const unsigned short* __restrict__ Alg,
             const unsigned short* __restrict__ Bhg,
             const unsigned short* __restrict__ Blg,
             const float* __restrict__ bias,
             float* __restrict__ C)
{
    __shared__ unsigned short AsH[128*32], AsL[128*32];
    __shared__ unsigned short BsH[128*32], BsL[128*32];

    const int tid  = threadIdx.x;
    const int w    = tid >> 6;
    const int lane = tid & 63;
    const int wm   = w >> 1;
    const int wn   = w & 1;
    const int bm   = blockIdx.x * 128;
    const int bn   = blockIdx.y * 128;

    const int srow = lane >> 2;
    const int skq  = (lane & 3) * 8;
    const size_t aoff = (size_t)(bm + w*32 + srow) * HH + skq;
    const size_t boff = (size_t)(bn + w*32 + srow) * HH + skq;
    const int lb = w * 32 * 32;

    const int fr = lane & 15;
    const int fk = (lane >> 4) * 8;
    const int ab = (wm*64 + fr)*32 + fk;
    const int bb = (wn*64 + fr)*32 + fk;

    f32x4 acc[4][4];
#pragma unroll
    for (int i = 0; i < 4; ++i)
#pragma unroll
        for (int j = 0; j < 4; ++j)
            acc[i][j] = (f32x4){0.f, 0.f, 0.f, 0.f};

    for (int k0 = 0; k0 < HH; k0 += 32) {
        __syncthreads();
        gload16(Ahg + aoff + k0,           AsH + lb);
        gload16(Ahg + aoff + 16*HH + k0,   AsH + lb + 512);
        gload16(Alg + aoff + k0,           AsL + lb);
        gload16(Alg + aoff + 16*HH + k0,   AsL + lb + 512);
        gload16(Bhg + boff + k0,           BsH + lb);
        gload16(Bhg + boff + 16*HH + k0,   BsH + lb + 512);
        gload16(Blg + boff + k0,           BsL + lb);
        gload16(Blg + boff + 16*HH + k0,   BsL + lb + 512);
        __syncthreads();

        bf16x8 ah[4], al[4], bh[4], bl[4];
#pragma unroll
        for (int i = 0; i < 4; ++i) {
            ah[i] = *(const bf16x8*)(AsH + ab + i*512);
            al[i] = *(const bf16x8*)(AsL + ab + i*512);
            bh[i] = *(const bf16x8*)(BsH + bb + i*512);
            bl[i] = *(const bf16x8*)(BsL + bb + i*512);
        }
#pragma unroll
        for (int i = 0; i < 4; ++i)
#pragma unroll
            for (int j = 0; j < 4; ++j) {
                acc[i][j] = __builtin_amdgcn_mfma_f32_16x16x32_bf16(ah[i], bh[j], acc[i][j], 0, 0, 0);
                acc[i][j] = __builtin_amdgcn_mfma_f32_16x16x32_bf16(al[i], bh[j], acc[i][j], 0, 0, 0);
                acc[i][j] = __builtin_amdgcn_mfma_f32_16x16x32_bf16(ah[i], bl[j], acc[i][j], 0, 0, 0);
            }
    }

    const int rr = (lane >> 4) * 4;
#pragma unroll
    for (int j = 0; j < 4; ++j) {
        const int col = bn + wn*64 + j*16 + fr;
        const float bz = bias[col];
#pragma unroll
        for (int i = 0; i < 4; ++i) {
            const int row = bm + wm*64 + i*16 + rr;
            float* cp = C + (size_t)row * VV + col;
#pragma unroll
            for (int r = 0; r < 4; ++r)
                cp[(size_t)r * VV] = acc[i][j][r] + bz;
        }
    }
}

// ---------------------------------------------------------------------------
extern "C" void kernel_launch(void* const* d_in, const int* in_sizes, int n_in,
                              void* d_out, int out_size, void* d_ws, size_t ws_size,
                              hipStream_t stream)
{
    const int*   x     = (const int*)d_in[0];
    const float* embed = (const float*)d_in[1];
    const float* W_ih  = (const float*)d_in[2];
    const float* W_hh  = (const float*)d_in[3];
    const float* b_ih  = (const float*)d_in[4];
    const float* b_hh  = (const float*)d_in[5];
    const float* fc_w  = (const float*)d_in[6];
    const float* fc_b  = (const float*)d_in[7];
    float* out = (float*)d_out;

    char* ws = (char*)d_ws;
    float* xg  = (float*)ws;  ws += (size_t)MBT * GG * 4;            // 64 MB
    unsigned short* WhH = (unsigned short*)ws; ws += (size_t)GG * HH * 2;  // 8 MB
    unsigned short* WhL = (unsigned short*)ws; ws += (size_t)GG * HH * 2;  // 8 MB
    unsigned short* hsH = (unsigned short*)ws; ws += (size_t)MBT * HH * 2; // 8 MB
    unsigned short* hsL = (unsigned short*)ws; ws += (size_t)MBT * HH * 2; // 8 MB
    float* hs32 = (float*)ws; ws += (size_t)MBT * HH * 4;            // 16.8 MB
    // zero-init region: cbuf + ping h buffers (contiguous)
    float* cbuf = (float*)ws; ws += (size_t)BB * HH * 4;             // 128 KB
    unsigned short* hA_hi = (unsigned short*)ws; ws += (size_t)BB * HH * 2;
    unsigned short* hA_lo = (unsigned short*)ws; ws += (size_t)BB * HH * 2;
    unsigned short* hB_hi = (unsigned short*)ws; ws += (size_t)BB * HH * 2;
    unsigned short* hB_lo = (unsigned short*)ws; ws += (size_t)BB * HH * 2;
    unsigned short* Bh = (unsigned short*)ws; ws += (size_t)VV * HH * 2;   // 65.5 MB
    unsigned short* Bl = (unsigned short*)ws; ws += (size_t)VV * HH * 2;   // 65.5 MB
    const size_t need = (size_t)(ws - (char*)d_ws);
    const bool fc_mfma = (ws_size >= need);

    // c0 = 0, h0(hi/lo) = 0  (one contiguous memset: cbuf + hA_hi + hA_lo)
    hipMemsetAsync(cbuf, 0, (size_t)BB * HH * (4 + 2 + 2), stream);

    // W_hh -> bf16 hi/lo (row-major [G][H], consumed directly as MFMA B)
    split_f32_bf16<<<dim3((GG * HH) / 1024), 256, 0, stream>>>(W_hh, WhH, WhL);

    if (fc_mfma) {
        split_f32_bf16<<<dim3((VV * HH) / 1024), 256, 0, stream>>>(fc_w, Bh, Bl);
    }

    // xg = embed[x] @ W_ih^T + b_ih + b_hh
    sgemm_nt<true><<<dim3(GG / 128, MBT / 128), 256, 0, stream>>>(
        embed, W_ih, xg, x, b_ih, b_hh, MBT, GG, EE);

    // sequential LSTM scan: one fused launch per step, ping-pong h
    for (int t = 0; t < TT; ++t) {
        const unsigned short* hi_in  = (t & 1) ? hB_hi : hA_hi;
        const unsigned short* lo_in  = (t & 1) ? hB_lo : hA_lo;
        unsigned short*       hi_out = (t & 1) ? hA_hi : hB_hi;
        unsigned short*       lo_out = (t & 1) ? hA_lo : hB_lo;
        lstm_step<<<dim3(HH / JB), 256, 0, stream>>>(
            WhH, WhL, hi_in, lo_in, xg, cbuf, hi_out, lo_out,
            hsH, hsL, hs32, t);
    }

    if (fc_mfma) {
        mfma_fc<<<dim3(MBT / 128, VV / 128), 256, 0, stream>>>(
            hsH, hsL, Bh, Bl, fc_b, out);
    } else {
        sgemm_nt<false><<<dim3(VV / 128, MBT / 128), 256, 0, stream>>>(
            hs32, fc_w, out, nullptr, fc_b, nullptr, MBT, VV, HH);
    }
}